// Round 1
// baseline (607.714 us; speedup 1.0000x reference)
//
#include <hip/hip_runtime.h>
#include <hip/hip_bf16.h>
#include <math.h>

// GAT encoder: 2 layers.
//   L1: h1 = x@W1 [N,256] -> per-head (H=2,C=128) attention softmax over dst-grouped
//       edges (incl self-loops), aggregate, +b1, ELU -> helu [N,256]
//   L2: h2 = helu@W2 [N,64], 1 head, aggregate, +b2 -> out [N,64]
// Strategy: device-built CSR by dst (histogram+scan+fill), then 1 wave / node
// gather-aggregate (no float atomics). GEMMs: fp32 vector, LDS-tiled.

#define NSLOPE 0.2f

// ---------------- CSR build ----------------
__global__ void k_init_deg(int* deg, int n) {
    int i = blockIdx.x * blockDim.x + threadIdx.x;
    if (i < n) deg[i] = 1;  // self-loop
}

__global__ void k_hist(const int* __restrict__ dst, int* deg, int E) {
    int i = blockIdx.x * blockDim.x + threadIdx.x;
    if (i < E) atomicAdd(&deg[dst[i]], 1);
}

__global__ __launch_bounds__(1024) void k_scan(const int* __restrict__ deg,
                                               int* __restrict__ off,
                                               int* __restrict__ cur, int n) {
    __shared__ int sd[1024];
    int t = threadIdx.x;
    int CH = (n + 1023) / 1024;
    int s = t * CH, e = min(s + CH, n);
    if (s > n) s = n;
    int loc = 0;
    for (int i = s; i < e; ++i) loc += deg[i];
    sd[t] = loc;
    __syncthreads();
    for (int o = 1; o < 1024; o <<= 1) {
        int v = (t >= o) ? sd[t - o] : 0;
        __syncthreads();
        sd[t] += v;
        __syncthreads();
    }
    int incl = sd[t];
    int run = incl - loc;
    for (int i = s; i < e; ++i) {
        int d = deg[i];
        off[i] = run; cur[i] = run;
        run += d;
    }
    if (t == 1023) off[n] = incl;
}

__global__ void k_fill(const int* __restrict__ src, const int* __restrict__ dst,
                       int* cur, int* __restrict__ srcl, int E, int N) {
    int i = blockIdx.x * blockDim.x + threadIdx.x;
    if (i >= E + N) return;
    int s, d;
    if (i < E) { s = src[i]; d = dst[i]; } else { s = d = i - E; }
    int p = atomicAdd(&cur[d], 1);
    srcl[p] = s;
}

// ---------------- GEMM1: [M,256]x[256,256] ----------------
__global__ __launch_bounds__(256) void k_gemm1(const float* __restrict__ x,
                                               const float* __restrict__ W,
                                               float* __restrict__ h, int M) {
    __shared__ float xs[32][64];   // [k][row] transposed
    __shared__ float ws[32][256];  // [k][col]
    int t = threadIdx.x;
    int tx = t & 31, ty = t >> 5;
    int row0 = blockIdx.x * 64;
    float acc[8][8];
#pragma unroll
    for (int i = 0; i < 8; ++i)
#pragma unroll
        for (int j = 0; j < 8; ++j) acc[i][j] = 0.f;

    for (int kc = 0; kc < 256; kc += 32) {
#pragma unroll
        for (int j = 0; j < 2; ++j) {
            int slot = t + j * 256;           // 0..511
            int r = slot >> 3, kg = slot & 7; // r:0..63, kg:0..7
            int row = row0 + r;
            float4 v = make_float4(0.f, 0.f, 0.f, 0.f);
            if (row < M) v = *(const float4*)&x[row * 256 + kc + kg * 4];
            xs[kg * 4 + 0][r] = v.x; xs[kg * 4 + 1][r] = v.y;
            xs[kg * 4 + 2][r] = v.z; xs[kg * 4 + 3][r] = v.w;
        }
#pragma unroll
        for (int j = 0; j < 8; ++j) {
            int slot = t + j * 256;            // 0..2047
            int k = slot >> 6, cg = slot & 63; // k:0..31, cg:0..63
            *(float4*)&ws[k][cg * 4] = *(const float4*)&W[(kc + k) * 256 + cg * 4];
        }
        __syncthreads();
#pragma unroll 8
        for (int k = 0; k < 32; ++k) {
            float a[8], b[8];
            *(float4*)&a[0] = *(float4*)&xs[k][ty * 8];
            *(float4*)&a[4] = *(float4*)&xs[k][ty * 8 + 4];
            *(float4*)&b[0] = *(float4*)&ws[k][tx * 8];
            *(float4*)&b[4] = *(float4*)&ws[k][tx * 8 + 4];
#pragma unroll
            for (int i = 0; i < 8; ++i)
#pragma unroll
                for (int j = 0; j < 8; ++j) acc[i][j] += a[i] * b[j];
        }
        __syncthreads();
    }
#pragma unroll
    for (int i = 0; i < 8; ++i) {
        int row = row0 + ty * 8 + i;
        if (row < M) {
            *(float4*)&h[row * 256 + tx * 8] =
                make_float4(acc[i][0], acc[i][1], acc[i][2], acc[i][3]);
            *(float4*)&h[row * 256 + tx * 8 + 4] =
                make_float4(acc[i][4], acc[i][5], acc[i][6], acc[i][7]);
        }
    }
}

// ---------------- GEMM2: [M,256]x[256,64] ----------------
__global__ __launch_bounds__(256) void k_gemm2(const float* __restrict__ x,
                                               const float* __restrict__ W,
                                               float* __restrict__ h, int M) {
    __shared__ float xs[64][128];  // [k][row]
    __shared__ float ws[64][64];   // [k][col]
    int t = threadIdx.x;
    int tx = t & 7, ty = t >> 3;  // tx:0..7 cols, ty:0..31 rows
    int row0 = blockIdx.x * 128;
    float acc[4][8];
#pragma unroll
    for (int i = 0; i < 4; ++i)
#pragma unroll
        for (int j = 0; j < 8; ++j) acc[i][j] = 0.f;

    for (int kc = 0; kc < 256; kc += 64) {
#pragma unroll
        for (int j = 0; j < 8; ++j) {
            int slot = t + j * 256;             // 0..2047
            int r = slot >> 4, kg = slot & 15;  // r:0..127, kg:0..15
            int row = row0 + r;
            float4 v = make_float4(0.f, 0.f, 0.f, 0.f);
            if (row < M) v = *(const float4*)&x[row * 256 + kc + kg * 4];
            xs[kg * 4 + 0][r] = v.x; xs[kg * 4 + 1][r] = v.y;
            xs[kg * 4 + 2][r] = v.z; xs[kg * 4 + 3][r] = v.w;
        }
#pragma unroll
        for (int j = 0; j < 4; ++j) {
            int slot = t + j * 256;             // 0..1023
            int k = slot >> 4, cg = slot & 15;  // k:0..63, cg:0..15
            *(float4*)&ws[k][cg * 4] = *(const float4*)&W[(kc + k) * 64 + cg * 4];
        }
        __syncthreads();
#pragma unroll 8
        for (int k = 0; k < 64; ++k) {
            float a[4], b[8];
            *(float4*)&a[0] = *(float4*)&xs[k][ty * 4];
            *(float4*)&b[0] = *(float4*)&ws[k][tx * 8];
            *(float4*)&b[4] = *(float4*)&ws[k][tx * 8 + 4];
#pragma unroll
            for (int i = 0; i < 4; ++i)
#pragma unroll
                for (int j = 0; j < 8; ++j) acc[i][j] += a[i] * b[j];
        }
        __syncthreads();
    }
#pragma unroll
    for (int i = 0; i < 4; ++i) {
        int row = row0 + ty * 4 + i;
        if (row < M) {
            *(float4*)&h[row * 64 + tx * 8] =
                make_float4(acc[i][0], acc[i][1], acc[i][2], acc[i][3]);
            *(float4*)&h[row * 64 + tx * 8 + 4] =
                make_float4(acc[i][4], acc[i][5], acc[i][6], acc[i][7]);
        }
    }
}

// ---------------- alpha dots ----------------
// one wave per node; h1 row 256 floats -> 2 heads of 128
__global__ __launch_bounds__(256) void k_alpha1(const float* __restrict__ h1,
                                                const float* __restrict__ a1s,
                                                const float* __restrict__ a1d,
                                                float* __restrict__ as,
                                                float* __restrict__ ad, int N) {
    int wid = (blockIdx.x * blockDim.x + threadIdx.x) >> 6;
    int lane = threadIdx.x & 63;
    if (wid >= N) return;
    float4 hv = *(const float4*)&h1[wid * 256 + lane * 4];
    float4 vs = *(const float4*)&a1s[lane * 4];
    float4 vd = *(const float4*)&a1d[lane * 4];
    float ps = hv.x * vs.x + hv.y * vs.y + hv.z * vs.z + hv.w * vs.w;
    float pd = hv.x * vd.x + hv.y * vd.y + hv.z * vd.z + hv.w * vd.w;
#pragma unroll
    for (int m = 1; m < 32; m <<= 1) {
        ps += __shfl_xor(ps, m, 64);
        pd += __shfl_xor(pd, m, 64);
    }
    if ((lane & 31) == 0) {
        int hh = lane >> 5;
        as[wid * 2 + hh] = ps;
        ad[wid * 2 + hh] = pd;
    }
}

__global__ __launch_bounds__(256) void k_alpha2(const float* __restrict__ h2,
                                                const float* __restrict__ a2s,
                                                const float* __restrict__ a2d,
                                                float* __restrict__ as,
                                                float* __restrict__ ad, int N) {
    int wid = (blockIdx.x * blockDim.x + threadIdx.x) >> 6;
    int lane = threadIdx.x & 63;
    if (wid >= N) return;
    float hv = h2[wid * 64 + lane];
    float ps = hv * a2s[lane];
    float pd = hv * a2d[lane];
#pragma unroll
    for (int m = 1; m < 64; m <<= 1) {
        ps += __shfl_xor(ps, m, 64);
        pd += __shfl_xor(pd, m, 64);
    }
    if (lane == 0) { as[wid] = ps; ad[wid] = pd; }
}

// ---------------- layer-1 aggregate (+bias+ELU) ----------------
// one wave per dst node; lane covers 4 channels (head = lane>>5)
__global__ __launch_bounds__(256) void k_agg1(const float* __restrict__ h1,
                                              const float* __restrict__ as,
                                              const float* __restrict__ ad,
                                              const int* __restrict__ off,
                                              const int* __restrict__ srcl,
                                              const float* __restrict__ b1,
                                              float* __restrict__ out, int N) {
    int wid = (blockIdx.x * blockDim.x + threadIdx.x) >> 6;
    int lane = threadIdx.x & 63;
    if (wid >= N) return;
    int p0 = off[wid], p1 = off[wid + 1];
    float ad0 = ad[wid * 2], ad1 = ad[wid * 2 + 1];
    float m0 = -1e30f, m1 = -1e30f;
    for (int p = p0 + lane; p < p1; p += 64) {
        int s = srcl[p];
        float l0 = as[s * 2] + ad0;     l0 = l0 >= 0.f ? l0 : NSLOPE * l0;
        float l1 = as[s * 2 + 1] + ad1; l1 = l1 >= 0.f ? l1 : NSLOPE * l1;
        m0 = fmaxf(m0, l0); m1 = fmaxf(m1, l1);
    }
#pragma unroll
    for (int m = 1; m < 64; m <<= 1) {
        m0 = fmaxf(m0, __shfl_xor(m0, m, 64));
        m1 = fmaxf(m1, __shfl_xor(m1, m, 64));
    }
    int head = lane >> 5;
    float adh = head ? ad1 : ad0;
    float mh = head ? m1 : m0;
    float4 acc = make_float4(0.f, 0.f, 0.f, 0.f);
    float sumw = 0.f;
    for (int p = p0; p < p1; ++p) {
        int s = srcl[p];
        float l = as[s * 2 + head] + adh;
        l = l >= 0.f ? l : NSLOPE * l;
        float w = __expf(l - mh);
        sumw += w;
        float4 hv = *(const float4*)&h1[s * 256 + lane * 4];
        acc.x += w * hv.x; acc.y += w * hv.y;
        acc.z += w * hv.z; acc.w += w * hv.w;
    }
    float inv = 1.0f / sumw;
    float4 bv = *(const float4*)&b1[lane * 4];
    float4 o;
    o.x = acc.x * inv + bv.x; o.y = acc.y * inv + bv.y;
    o.z = acc.z * inv + bv.z; o.w = acc.w * inv + bv.w;
    o.x = o.x > 0.f ? o.x : expm1f(o.x);
    o.y = o.y > 0.f ? o.y : expm1f(o.y);
    o.z = o.z > 0.f ? o.z : expm1f(o.z);
    o.w = o.w > 0.f ? o.w : expm1f(o.w);
    *(float4*)&out[wid * 256 + lane * 4] = o;
}

// ---------------- layer-2 aggregate (+bias) ----------------
__global__ __launch_bounds__(256) void k_agg2(const float* __restrict__ h2,
                                              const float* __restrict__ as,
                                              const float* __restrict__ ad,
                                              const int* __restrict__ off,
                                              const int* __restrict__ srcl,
                                              const float* __restrict__ b2,
                                              float* __restrict__ out, int N) {
    int wid = (blockIdx.x * blockDim.x + threadIdx.x) >> 6;
    int lane = threadIdx.x & 63;
    if (wid >= N) return;
    int p0 = off[wid], p1 = off[wid + 1];
    float adw = ad[wid];
    float mm = -1e30f;
    for (int p = p0 + lane; p < p1; p += 64) {
        int s = srcl[p];
        float l = as[s] + adw;
        l = l >= 0.f ? l : NSLOPE * l;
        mm = fmaxf(mm, l);
    }
#pragma unroll
    for (int m = 1; m < 64; m <<= 1) mm = fmaxf(mm, __shfl_xor(mm, m, 64));
    float acc = 0.f, sumw = 0.f;
    for (int p = p0; p < p1; ++p) {
        int s = srcl[p];
        float l = as[s] + adw;
        l = l >= 0.f ? l : NSLOPE * l;
        float w = __expf(l - mm);
        sumw += w;
        acc += w * h2[s * 64 + lane];
    }
    out[wid * 64 + lane] = acc / sumw + b2[lane];
}

// ---------------- launch ----------------
extern "C" void kernel_launch(void* const* d_in, const int* in_sizes, int n_in,
                              void* d_out, int out_size, void* d_ws, size_t ws_size,
                              hipStream_t stream) {
    if (n_in < 10) return;
    const float* x   = (const float*)d_in[0];
    const int*   ei  = (const int*)d_in[1];   // harness delivers integer inputs as int32
    const float* W1  = (const float*)d_in[2];
    const float* a1s = (const float*)d_in[3];
    const float* a1d = (const float*)d_in[4];
    const float* b1  = (const float*)d_in[5];
    const float* W2  = (const float*)d_in[6];
    const float* a2s = (const float*)d_in[7];
    const float* a2d = (const float*)d_in[8];
    const float* b2  = (const float*)d_in[9];
    float* out = (float*)d_out;

    const int N = in_sizes[0] / 256;
    const int E = in_sizes[1] / 2;
    const int* esrc = ei;
    const int* edst = ei + E;

    // workspace layout (256B aligned)
    char* ws = (char*)d_ws;
    size_t o = 0;
    auto alloc = [&](size_t bytes) -> void* {
        void* p = ws + o;
        o = (o + bytes + 255) & ~(size_t)255;
        return p;
    };
    float* h1   = (float*)alloc((size_t)N * 256 * 4);
    float* helu = (float*)alloc((size_t)N * 256 * 4);
    float* h2   = (float*)alloc((size_t)N * 64 * 4);
    float* al1s = (float*)alloc((size_t)N * 2 * 4);
    float* al1d = (float*)alloc((size_t)N * 2 * 4);
    float* al2s = (float*)alloc((size_t)N * 4);
    float* al2d = (float*)alloc((size_t)N * 4);
    int* deg  = (int*)alloc((size_t)N * 4);
    int* off  = (int*)alloc((size_t)(N + 1) * 4);
    int* cur  = (int*)alloc((size_t)N * 4);
    int* srcl = (int*)alloc((size_t)(E + N) * 4);
    if (o > ws_size) return;  // workspace too small; bail deterministically

    // CSR build
    k_init_deg<<<(N + 255) / 256, 256, 0, stream>>>(deg, N);
    k_hist<<<(E + 255) / 256, 256, 0, stream>>>(edst, deg, E);
    k_scan<<<1, 1024, 0, stream>>>(deg, off, cur, N);
    k_fill<<<(E + N + 255) / 256, 256, 0, stream>>>(esrc, edst, cur, srcl, E, N);

    // layer 1
    k_gemm1<<<(N + 63) / 64, 256, 0, stream>>>(x, W1, h1, N);
    k_alpha1<<<(N + 3) / 4, 256, 0, stream>>>(h1, a1s, a1d, al1s, al1d, N);
    k_agg1<<<(N + 3) / 4, 256, 0, stream>>>(h1, al1s, al1d, off, srcl, b1, helu, N);

    // layer 2
    k_gemm2<<<(N + 127) / 128, 256, 0, stream>>>(helu, W2, h2, N);
    k_alpha2<<<(N + 3) / 4, 256, 0, stream>>>(h2, a2s, a2d, al2s, al2d, N);
    k_agg2<<<(N + 3) / 4, 256, 0, stream>>>(h2, al2s, al2d, off, srcl, b2, out, N);
}

// Round 2
// 449.092 us; speedup vs baseline: 1.3532x; 1.3532x over previous
//
#include <hip/hip_runtime.h>
#include <hip/hip_bf16.h>
#include <math.h>

// GAT encoder, round 2.
//  - CSR build: histogram + 2-level parallel scan + atomic fill.
//  - gemm1 (x@W1): fp32, 64x128 tiles, conflict-free LDS mapping, alpha1 fused.
//  - agg1: wave/node, shuffle-broadcast edge batching, bias+ELU fused.
//  - gemm2 (helu@W2): fp32, 64x64 tiles, alpha2 fused.
//  - agg2: wave/node batched, +b2 -> out.

#define NSLOPE 0.2f

// ---------------- CSR build ----------------
__global__ void k_init_deg(int* deg, int n) {
    int i = blockIdx.x * blockDim.x + threadIdx.x;
    if (i < n) deg[i] = 1;  // self-loop
}

__global__ void k_hist(const int* __restrict__ dst, int* deg, int E) {
    int i = blockIdx.x * blockDim.x + threadIdx.x;
    if (i < E) atomicAdd(&deg[dst[i]], 1);
}

// 2-level scan: a) per-block sums, b) scan of 256 partials, c) per-block rescan
__global__ __launch_bounds__(256) void k_scan_a(const int* __restrict__ deg,
                                                int* __restrict__ part, int n, int CH) {
    __shared__ int sd[256];
    int b = blockIdx.x, t = threadIdx.x;
    int s = b * CH, e = min(n, s + CH);
    int loc = 0;
    for (int i = s + t; i < e; i += 256) loc += deg[i];
    sd[t] = loc;
    __syncthreads();
    for (int o = 128; o > 0; o >>= 1) {
        if (t < o) sd[t] += sd[t + o];
        __syncthreads();
    }
    if (t == 0) part[b] = sd[0];
}

__global__ __launch_bounds__(256) void k_scan_b(int* part, int* off_n) {
    __shared__ int sd[256];
    int t = threadIdx.x;
    int v = part[t];
    sd[t] = v;
    __syncthreads();
    for (int o = 1; o < 256; o <<= 1) {
        int u = (t >= o) ? sd[t - o] : 0;
        __syncthreads();
        sd[t] += u;
        __syncthreads();
    }
    part[t] = sd[t] - v;  // exclusive base per block
    if (t == 255) *off_n = sd[255];
}

__global__ __launch_bounds__(256) void k_scan_c(const int* __restrict__ deg,
                                                const int* __restrict__ part,
                                                int* __restrict__ off,
                                                int* __restrict__ cur, int n, int CH) {
    __shared__ int sd[256];
    int b = blockIdx.x, t = threadIdx.x;
    int s = b * CH, e = min(n, s + CH);
    int base = part[b];
    for (int c = s; c < e; c += 256) {
        int i = c + t;
        int v = (i < e) ? deg[i] : 0;
        sd[t] = v;
        __syncthreads();
        for (int o = 1; o < 256; o <<= 1) {
            int u = (t >= o) ? sd[t - o] : 0;
            __syncthreads();
            sd[t] += u;
            __syncthreads();
        }
        if (i < e) {
            int ex = base + sd[t] - v;
            off[i] = ex; cur[i] = ex;
        }
        base += sd[255];
        __syncthreads();
    }
}

__global__ void k_fill(const int* __restrict__ src, const int* __restrict__ dst,
                       int* cur, int* __restrict__ srcl, int E, int N) {
    int i = blockIdx.x * blockDim.x + threadIdx.x;
    if (i >= E + N) return;
    int s, d;
    if (i < E) { s = src[i]; d = dst[i]; } else { s = d = i - E; }
    int p = atomicAdd(&cur[d], 1);
    srcl[p] = s;
}

// ---------------- GEMM1: [M,256]x[256,256], 64x128 tile, alpha1 fused ----------
// grid (ceil(M/64), 2); blockIdx.y = head (cols head*128..+127)
__global__ __launch_bounds__(256) void k_gemm1(const float* __restrict__ x,
                                               const float* __restrict__ W,
                                               const float* __restrict__ a1s,
                                               const float* __restrict__ a1d,
                                               float* __restrict__ h,
                                               float* __restrict__ as_,
                                               float* __restrict__ ad_, int M) {
    __shared__ float xs[32][68];    // [k][row], stride 68 (272B, 16B-aligned)
    __shared__ float ws[32][132];   // [k][col], stride 132 (528B, 16B-aligned)
    int t = threadIdx.x;
    int tx = t & 15, ty = t >> 4;   // tx: col groups, ty: row group
    int row0 = blockIdx.x * 64;
    int head = blockIdx.y;
    int col0 = head * 128;
    float acc[4][8];
#pragma unroll
    for (int i = 0; i < 4; ++i)
#pragma unroll
        for (int j = 0; j < 8; ++j) acc[i][j] = 0.f;

    for (int kc = 0; kc < 256; kc += 32) {
        // stage x: 64 rows x 32 k (transposed)
#pragma unroll
        for (int j = 0; j < 2; ++j) {
            int slot = t + j * 256;            // 0..511
            int r = slot >> 3, kg = slot & 7;  // r:0..63, kg:0..7
            int row = row0 + r;
            float4 v = make_float4(0.f, 0.f, 0.f, 0.f);
            if (row < M) v = *(const float4*)&x[(size_t)row * 256 + kc + kg * 4];
            xs[kg * 4 + 0][r] = v.x; xs[kg * 4 + 1][r] = v.y;
            xs[kg * 4 + 2][r] = v.z; xs[kg * 4 + 3][r] = v.w;
        }
        // stage W: 32 k x 128 cols
#pragma unroll
        for (int j = 0; j < 4; ++j) {
            int slot = t + j * 256;             // 0..1023
            int k = slot >> 5, cg = slot & 31;  // k:0..31, cg:0..31
            *(float4*)&ws[k][cg * 4] =
                *(const float4*)&W[(size_t)(kc + k) * 256 + col0 + cg * 4];
        }
        __syncthreads();
#pragma unroll 8
        for (int k = 0; k < 32; ++k) {
            float4 a  = *(const float4*)&xs[k][ty * 4];
            float4 b0 = *(const float4*)&ws[k][tx * 4];
            float4 b1 = *(const float4*)&ws[k][64 + tx * 4];
            float av[4] = {a.x, a.y, a.z, a.w};
            float bv[8] = {b0.x, b0.y, b0.z, b0.w, b1.x, b1.y, b1.z, b1.w};
#pragma unroll
            for (int i = 0; i < 4; ++i)
#pragma unroll
                for (int j = 0; j < 8; ++j) acc[i][j] += av[i] * bv[j];
        }
        __syncthreads();
    }

    // epilogue: store h + fused alpha dots (pre-bias h, per PyG)
    float4 s0 = *(const float4*)&a1s[head * 128 + tx * 4];
    float4 s1 = *(const float4*)&a1s[head * 128 + 64 + tx * 4];
    float4 d0 = *(const float4*)&a1d[head * 128 + tx * 4];
    float4 d1 = *(const float4*)&a1d[head * 128 + 64 + tx * 4];
#pragma unroll
    for (int i = 0; i < 4; ++i) {
        int row = row0 + ty * 4 + i;
        float ps = acc[i][0] * s0.x + acc[i][1] * s0.y + acc[i][2] * s0.z + acc[i][3] * s0.w
                 + acc[i][4] * s1.x + acc[i][5] * s1.y + acc[i][6] * s1.z + acc[i][7] * s1.w;
        float pd = acc[i][0] * d0.x + acc[i][1] * d0.y + acc[i][2] * d0.z + acc[i][3] * d0.w
                 + acc[i][4] * d1.x + acc[i][5] * d1.y + acc[i][6] * d1.z + acc[i][7] * d1.w;
#pragma unroll
        for (int m = 1; m < 16; m <<= 1) {
            ps += __shfl_xor(ps, m, 64);
            pd += __shfl_xor(pd, m, 64);
        }
        if (row < M) {
            *(float4*)&h[(size_t)row * 256 + col0 + tx * 4] =
                make_float4(acc[i][0], acc[i][1], acc[i][2], acc[i][3]);
            *(float4*)&h[(size_t)row * 256 + col0 + 64 + tx * 4] =
                make_float4(acc[i][4], acc[i][5], acc[i][6], acc[i][7]);
            if (tx == 0) {
                as_[row * 2 + head] = ps;
                ad_[row * 2 + head] = pd;
            }
        }
    }
}

// ---------------- GEMM2: [M,256]x[256,64], 64x64 tile, alpha2 fused ----------
__global__ __launch_bounds__(128) void k_gemm2(const float* __restrict__ x,
                                               const float* __restrict__ W,
                                               const float* __restrict__ a2s,
                                               const float* __restrict__ a2d,
                                               float* __restrict__ h,
                                               float* __restrict__ as_,
                                               float* __restrict__ ad_, int M) {
    __shared__ float xs[32][68];
    __shared__ float ws[32][68];
    int t = threadIdx.x;
    int tx = t & 7, ty = t >> 3;   // tx: 8 col groups, ty: 16 row groups
    int row0 = blockIdx.x * 64;
    float acc[4][8];
#pragma unroll
    for (int i = 0; i < 4; ++i)
#pragma unroll
        for (int j = 0; j < 8; ++j) acc[i][j] = 0.f;

    for (int kc = 0; kc < 256; kc += 32) {
#pragma unroll
        for (int j = 0; j < 4; ++j) {
            int slot = t + j * 128;            // 0..511
            int r = slot >> 3, kg = slot & 7;  // r:0..63
            int row = row0 + r;
            float4 v = make_float4(0.f, 0.f, 0.f, 0.f);
            if (row < M) v = *(const float4*)&x[(size_t)row * 256 + kc + kg * 4];
            xs[kg * 4 + 0][r] = v.x; xs[kg * 4 + 1][r] = v.y;
            xs[kg * 4 + 2][r] = v.z; xs[kg * 4 + 3][r] = v.w;
        }
#pragma unroll
        for (int j = 0; j < 4; ++j) {
            int slot = t + j * 128;             // 0..511
            int k = slot >> 4, cg = slot & 15;  // k:0..31, cg:0..15
            *(float4*)&ws[k][cg * 4] =
                *(const float4*)&W[(size_t)(kc + k) * 64 + cg * 4];
        }
        __syncthreads();
#pragma unroll 8
        for (int k = 0; k < 32; ++k) {
            float4 a  = *(const float4*)&xs[k][ty * 4];
            float4 b0 = *(const float4*)&ws[k][tx * 4];
            float4 b1 = *(const float4*)&ws[k][32 + tx * 4];
            float av[4] = {a.x, a.y, a.z, a.w};
            float bv[8] = {b0.x, b0.y, b0.z, b0.w, b1.x, b1.y, b1.z, b1.w};
#pragma unroll
            for (int i = 0; i < 4; ++i)
#pragma unroll
                for (int j = 0; j < 8; ++j) acc[i][j] += av[i] * bv[j];
        }
        __syncthreads();
    }

    float4 s0 = *(const float4*)&a2s[tx * 4];
    float4 s1 = *(const float4*)&a2s[32 + tx * 4];
    float4 d0 = *(const float4*)&a2d[tx * 4];
    float4 d1 = *(const float4*)&a2d[32 + tx * 4];
#pragma unroll
    for (int i = 0; i < 4; ++i) {
        int row = row0 + ty * 4 + i;
        float ps = acc[i][0] * s0.x + acc[i][1] * s0.y + acc[i][2] * s0.z + acc[i][3] * s0.w
                 + acc[i][4] * s1.x + acc[i][5] * s1.y + acc[i][6] * s1.z + acc[i][7] * s1.w;
        float pd = acc[i][0] * d0.x + acc[i][1] * d0.y + acc[i][2] * d0.z + acc[i][3] * d0.w
                 + acc[i][4] * d1.x + acc[i][5] * d1.y + acc[i][6] * d1.z + acc[i][7] * d1.w;
#pragma unroll
        for (int m = 1; m < 8; m <<= 1) {
            ps += __shfl_xor(ps, m, 64);
            pd += __shfl_xor(pd, m, 64);
        }
        if (row < M) {
            *(float4*)&h[(size_t)row * 64 + tx * 4] =
                make_float4(acc[i][0], acc[i][1], acc[i][2], acc[i][3]);
            *(float4*)&h[(size_t)row * 64 + 32 + tx * 4] =
                make_float4(acc[i][4], acc[i][5], acc[i][6], acc[i][7]);
            if (tx == 0) {
                as_[row] = ps;
                ad_[row] = pd;
            }
        }
    }
}

// ---------------- layer-1 aggregate (+bias+ELU), batched ----------------
__global__ __launch_bounds__(256) void k_agg1(const float* __restrict__ h1,
                                              const float* __restrict__ as,
                                              const float* __restrict__ ad,
                                              const int* __restrict__ off,
                                              const int* __restrict__ srcl,
                                              const float* __restrict__ b1,
                                              float* __restrict__ out, int N) {
    int wid = (blockIdx.x * blockDim.x + threadIdx.x) >> 6;
    int lane = threadIdx.x & 63;
    if (wid >= N) return;
    int p0 = off[wid], p1 = off[wid + 1];
    float ad0 = ad[wid * 2], ad1 = ad[wid * 2 + 1];
    // pass 1: max per head
    float m0 = -1e30f, m1 = -1e30f;
    for (int p = p0 + lane; p < p1; p += 64) {
        int s = srcl[p];
        float l0 = as[s * 2] + ad0;     l0 = l0 >= 0.f ? l0 : NSLOPE * l0;
        float l1 = as[s * 2 + 1] + ad1; l1 = l1 >= 0.f ? l1 : NSLOPE * l1;
        m0 = fmaxf(m0, l0); m1 = fmaxf(m1, l1);
    }
#pragma unroll
    for (int m = 1; m < 64; m <<= 1) {
        m0 = fmaxf(m0, __shfl_xor(m0, m, 64));
        m1 = fmaxf(m1, __shfl_xor(m1, m, 64));
    }
    int head = lane >> 5;
    float4 acc = make_float4(0.f, 0.f, 0.f, 0.f);
    float sumw = 0.f;
    // pass 2: 64-edge chunks, shuffle-broadcast
    for (int base = p0; base < p1; base += 64) {
        int p = base + lane;
        int cnt = min(64, p1 - base);
        int s = 0; float w0 = 0.f, w1 = 0.f;
        if (p < p1) {
            s = srcl[p];
            float l0 = as[s * 2] + ad0;     l0 = l0 >= 0.f ? l0 : NSLOPE * l0;
            float l1 = as[s * 2 + 1] + ad1; l1 = l1 >= 0.f ? l1 : NSLOPE * l1;
            w0 = __expf(l0 - m0); w1 = __expf(l1 - m1);
        }
        for (int j = 0; j < cnt; ++j) {
            int sj = __shfl(s, j, 64);
            float wj0 = __shfl(w0, j, 64);
            float wj1 = __shfl(w1, j, 64);
            float wj = head ? wj1 : wj0;
            sumw += wj;
            float4 hv = *(const float4*)&h1[(size_t)sj * 256 + lane * 4];
            acc.x += wj * hv.x; acc.y += wj * hv.y;
            acc.z += wj * hv.z; acc.w += wj * hv.w;
        }
    }
    float inv = 1.0f / sumw;
    float4 bv = *(const float4*)&b1[lane * 4];
    float4 o;
    o.x = acc.x * inv + bv.x; o.y = acc.y * inv + bv.y;
    o.z = acc.z * inv + bv.z; o.w = acc.w * inv + bv.w;
    o.x = o.x > 0.f ? o.x : expm1f(o.x);
    o.y = o.y > 0.f ? o.y : expm1f(o.y);
    o.z = o.z > 0.f ? o.z : expm1f(o.z);
    o.w = o.w > 0.f ? o.w : expm1f(o.w);
    *(float4*)&out[(size_t)wid * 256 + lane * 4] = o;
}

// ---------------- layer-2 aggregate (+bias), batched ----------------
__global__ __launch_bounds__(256) void k_agg2(const float* __restrict__ h2,
                                              const float* __restrict__ as,
                                              const float* __restrict__ ad,
                                              const int* __restrict__ off,
                                              const int* __restrict__ srcl,
                                              const float* __restrict__ b2,
                                              float* __restrict__ out, int N) {
    int wid = (blockIdx.x * blockDim.x + threadIdx.x) >> 6;
    int lane = threadIdx.x & 63;
    if (wid >= N) return;
    int p0 = off[wid], p1 = off[wid + 1];
    float adw = ad[wid];
    float mm = -1e30f;
    for (int p = p0 + lane; p < p1; p += 64) {
        int s = srcl[p];
        float l = as[s] + adw;
        l = l >= 0.f ? l : NSLOPE * l;
        mm = fmaxf(mm, l);
    }
#pragma unroll
    for (int m = 1; m < 64; m <<= 1) mm = fmaxf(mm, __shfl_xor(mm, m, 64));
    float acc = 0.f, sumw = 0.f;
    for (int base = p0; base < p1; base += 64) {
        int p = base + lane;
        int cnt = min(64, p1 - base);
        int s = 0; float w = 0.f;
        if (p < p1) {
            s = srcl[p];
            float l = as[s] + adw;
            l = l >= 0.f ? l : NSLOPE * l;
            w = __expf(l - mm);
        }
        for (int j = 0; j < cnt; ++j) {
            int sj = __shfl(s, j, 64);
            float wj = __shfl(w, j, 64);
            sumw += wj;
            acc += wj * h2[(size_t)sj * 64 + lane];
        }
    }
    out[(size_t)wid * 64 + lane] = acc / sumw + b2[lane];
}

// ---------------- launch ----------------
extern "C" void kernel_launch(void* const* d_in, const int* in_sizes, int n_in,
                              void* d_out, int out_size, void* d_ws, size_t ws_size,
                              hipStream_t stream) {
    if (n_in < 10) return;
    const float* x   = (const float*)d_in[0];
    const int*   ei  = (const int*)d_in[1];
    const float* W1  = (const float*)d_in[2];
    const float* a1s = (const float*)d_in[3];
    const float* a1d = (const float*)d_in[4];
    const float* b1  = (const float*)d_in[5];
    const float* W2  = (const float*)d_in[6];
    const float* a2s = (const float*)d_in[7];
    const float* a2d = (const float*)d_in[8];
    const float* b2  = (const float*)d_in[9];
    float* out = (float*)d_out;

    const int N = in_sizes[0] / 256;
    const int E = in_sizes[1] / 2;
    const int* esrc = ei;
    const int* edst = ei + E;

    char* ws = (char*)d_ws;
    size_t o = 0;
    auto alloc = [&](size_t bytes) -> void* {
        void* p = ws + o;
        o = (o + bytes + 255) & ~(size_t)255;
        return p;
    };
    float* h1   = (float*)alloc((size_t)N * 256 * 4);
    float* helu = (float*)alloc((size_t)N * 256 * 4);
    float* h2   = (float*)alloc((size_t)N * 64 * 4);
    float* al1s = (float*)alloc((size_t)N * 2 * 4);
    float* al1d = (float*)alloc((size_t)N * 2 * 4);
    float* al2s = (float*)alloc((size_t)N * 4);
    float* al2d = (float*)alloc((size_t)N * 4);
    int* deg  = (int*)alloc((size_t)N * 4);
    int* off  = (int*)alloc((size_t)(N + 1) * 4);
    int* cur  = (int*)alloc((size_t)N * 4);
    int* part = (int*)alloc(256 * 4);
    int* srcl = (int*)alloc((size_t)(E + N) * 4);
    if (o > ws_size) return;

    const int CH = (N + 255) / 256;

    // CSR build
    k_init_deg<<<(N + 255) / 256, 256, 0, stream>>>(deg, N);
    k_hist<<<(E + 255) / 256, 256, 0, stream>>>(edst, deg, E);
    k_scan_a<<<256, 256, 0, stream>>>(deg, part, N, CH);
    k_scan_b<<<1, 256, 0, stream>>>(part, &off[N]);
    k_scan_c<<<256, 256, 0, stream>>>(deg, part, off, cur, N, CH);
    k_fill<<<(E + N + 255) / 256, 256, 0, stream>>>(esrc, edst, cur, srcl, E, N);

    // layer 1
    dim3 g1((N + 63) / 64, 2);
    k_gemm1<<<g1, 256, 0, stream>>>(x, W1, a1s, a1d, h1, al1s, al1d, N);
    k_agg1<<<(N + 3) / 4, 256, 0, stream>>>(h1, al1s, al1d, off, srcl, b1, helu, N);

    // layer 2
    k_gemm2<<<(N + 63) / 64, 128, 0, stream>>>(helu, W2, a2s, a2d, h2, al2s, al2d, N);
    k_agg2<<<(N + 3) / 4, 256, 0, stream>>>(h2, al2s, al2d, off, srcl, b2, out, N);
}

// Round 3
// 372.298 us; speedup vs baseline: 1.6323x; 1.2063x over previous
//
#include <hip/hip_runtime.h>
#include <hip/hip_bf16.h>
#include <math.h>

// GAT encoder, round 3.
//  - gemm1 (x@W1): split-bf16 MFMA (3-term hi/lo), 128x128 tiles, h1 stored bf16.
//  - prep kernels split x and W1 into bf16 hi/lo (W1 also transposed to [n][k]).
//  - alpha1: wave/node dot from bf16 h1.
//  - agg1/agg2: single-pass softmax (no max shift; logits bounded), bf16 gathers.
//  - gemm2: fp32 vector 64x64 (alpha2 fused), h2 stored bf16.

#define NSLOPE 0.2f

using bf16x8 = __attribute__((ext_vector_type(8))) short;
using f32x4  = __attribute__((ext_vector_type(4))) float;
using u16x8  = __attribute__((ext_vector_type(8))) unsigned short;
using u16x4  = __attribute__((ext_vector_type(4))) unsigned short;

__device__ __forceinline__ unsigned short bf16_rne(float f) {
    unsigned u = __float_as_uint(f);
    return (unsigned short)((u + 0x7FFFu + ((u >> 16) & 1u)) >> 16);
}
__device__ __forceinline__ float bf16_to_f(unsigned short h) {
    return __uint_as_float(((unsigned)h) << 16);
}

// ---------------- CSR build ----------------
__global__ void k_init_deg(int* deg, int n) {
    int i = blockIdx.x * blockDim.x + threadIdx.x;
    if (i < n) deg[i] = 1;  // self-loop
}

__global__ void k_hist(const int* __restrict__ dst, int* deg, int E) {
    int i = blockIdx.x * blockDim.x + threadIdx.x;
    if (i < E) atomicAdd(&deg[dst[i]], 1);
}

__global__ __launch_bounds__(256) void k_scan_a(const int* __restrict__ deg,
                                                int* __restrict__ part, int n, int CH) {
    __shared__ int sd[256];
    int b = blockIdx.x, t = threadIdx.x;
    int s = b * CH, e = min(n, s + CH);
    int loc = 0;
    for (int i = s + t; i < e; i += 256) loc += deg[i];
    sd[t] = loc;
    __syncthreads();
    for (int o = 128; o > 0; o >>= 1) {
        if (t < o) sd[t] += sd[t + o];
        __syncthreads();
    }
    if (t == 0) part[b] = sd[0];
}

__global__ __launch_bounds__(256) void k_scan_b(int* part, int* off_n) {
    __shared__ int sd[256];
    int t = threadIdx.x;
    int v = part[t];
    sd[t] = v;
    __syncthreads();
    for (int o = 1; o < 256; o <<= 1) {
        int u = (t >= o) ? sd[t - o] : 0;
        __syncthreads();
        sd[t] += u;
        __syncthreads();
    }
    part[t] = sd[t] - v;
    if (t == 255) *off_n = sd[255];
}

__global__ __launch_bounds__(256) void k_scan_c(const int* __restrict__ deg,
                                                const int* __restrict__ part,
                                                int* __restrict__ off,
                                                int* __restrict__ cur, int n, int CH) {
    __shared__ int sd[256];
    int b = blockIdx.x, t = threadIdx.x;
    int s = b * CH, e = min(n, s + CH);
    int base = part[b];
    for (int c = s; c < e; c += 256) {
        int i = c + t;
        int v = (i < e) ? deg[i] : 0;
        sd[t] = v;
        __syncthreads();
        for (int o = 1; o < 256; o <<= 1) {
            int u = (t >= o) ? sd[t - o] : 0;
            __syncthreads();
            sd[t] += u;
            __syncthreads();
        }
        if (i < e) {
            int ex = base + sd[t] - v;
            off[i] = ex; cur[i] = ex;
        }
        base += sd[255];
        __syncthreads();
    }
}

__global__ void k_fill(const int* __restrict__ src, const int* __restrict__ dst,
                       int* cur, int* __restrict__ srcl, int E, int N) {
    int i = blockIdx.x * blockDim.x + threadIdx.x;
    if (i >= E + N) return;
    int s, d;
    if (i < E) { s = src[i]; d = dst[i]; } else { s = d = i - E; }
    int p = atomicAdd(&cur[d], 1);
    srcl[p] = s;
}

// ---------------- prep: split W1 (and transpose to [n][k]) ----------------
__global__ __launch_bounds__(256) void k_prepw(const float* __restrict__ W,
                                               unsigned short* __restrict__ Whi,
                                               unsigned short* __restrict__ Wlo) {
    int id = blockIdx.x * 256 + threadIdx.x;  // 16384 threads
    int n = id >> 6, kg = id & 63;
    unsigned short hi[4], lo[4];
#pragma unroll
    for (int c = 0; c < 4; ++c) {
        float w = W[(kg * 4 + c) * 256 + n];
        unsigned short h = bf16_rne(w);
        hi[c] = h;
        lo[c] = bf16_rne(w - bf16_to_f(h));
    }
    *(u16x4*)&Whi[n * 256 + kg * 4] = *(u16x4*)hi;
    *(u16x4*)&Wlo[n * 256 + kg * 4] = *(u16x4*)lo;
}

// ---------------- prep: split x ----------------
__global__ __launch_bounds__(256) void k_prepx(const float* __restrict__ x,
                                               unsigned short* __restrict__ Xhi,
                                               unsigned short* __restrict__ Xlo,
                                               int total4) {
    int id = blockIdx.x * 256 + threadIdx.x;
    if (id >= total4) return;
    float4 v = *(const float4*)&x[(size_t)id * 4];
    float vv[4] = {v.x, v.y, v.z, v.w};
    unsigned short hi[4], lo[4];
#pragma unroll
    for (int c = 0; c < 4; ++c) {
        unsigned short h = bf16_rne(vv[c]);
        hi[c] = h;
        lo[c] = bf16_rne(vv[c] - bf16_to_f(h));
    }
    *(u16x4*)&Xhi[(size_t)id * 4] = *(u16x4*)hi;
    *(u16x4*)&Xlo[(size_t)id * 4] = *(u16x4*)lo;
}

// ---------------- GEMM1: split-bf16 MFMA, 128x128 tile ----------------
// grid (ceil(M/128), 2); blockIdx.y = head. Output h1b bf16 [M][256].
#define G1S 40  // LDS row stride (32 k + 8 pad) in ushort
__global__ __launch_bounds__(256) void k_gemm1(const unsigned short* __restrict__ Xhi,
                                               const unsigned short* __restrict__ Xlo,
                                               const unsigned short* __restrict__ Whi,
                                               const unsigned short* __restrict__ Wlo,
                                               unsigned short* __restrict__ h1b, int M) {
    __shared__ unsigned short sAh[128 * G1S], sAl[128 * G1S];
    __shared__ unsigned short sBh[128 * G1S], sBl[128 * G1S];
    int t = threadIdx.x;
    int lane = t & 63, wave = t >> 6;
    int q = lane >> 4, m = lane & 15;
    int row0 = blockIdx.x * 128;
    int col0 = blockIdx.y * 128;
    int rbase = (wave & 1) * 64, cbase = (wave >> 1) * 64;
    f32x4 acc[4][4];
#pragma unroll
    for (int i = 0; i < 4; ++i)
#pragma unroll
        for (int j = 0; j < 4; ++j) acc[i][j] = (f32x4){0.f, 0.f, 0.f, 0.f};

    for (int kc = 0; kc < 256; kc += 32) {
        // stage A: 128 rows x 32 k (hi+lo), 512 u16x8 slots per array
#pragma unroll
        for (int i = 0; i < 2; ++i) {
            int slot = t + i * 256;
            int r = slot >> 2, kg = slot & 3;
            int row = row0 + r;
            u16x8 vh = {0, 0, 0, 0, 0, 0, 0, 0};
            u16x8 vl = {0, 0, 0, 0, 0, 0, 0, 0};
            if (row < M) {
                vh = *(const u16x8*)&Xhi[(size_t)row * 256 + kc + kg * 8];
                vl = *(const u16x8*)&Xlo[(size_t)row * 256 + kc + kg * 8];
            }
            *(u16x8*)&sAh[r * G1S + kg * 8] = vh;
            *(u16x8*)&sAl[r * G1S + kg * 8] = vl;
        }
        // stage B: 128 cols x 32 k (hi+lo) from pre-transposed W [n][k]
#pragma unroll
        for (int i = 0; i < 2; ++i) {
            int slot = t + i * 256;
            int n = slot >> 2, kg = slot & 3;
            *(u16x8*)&sBh[n * G1S + kg * 8] =
                *(const u16x8*)&Whi[(size_t)(col0 + n) * 256 + kc + kg * 8];
            *(u16x8*)&sBl[n * G1S + kg * 8] =
                *(const u16x8*)&Wlo[(size_t)(col0 + n) * 256 + kc + kg * 8];
        }
        __syncthreads();
        bf16x8 ah[4], al[4], bh[4], bl[4];
#pragma unroll
        for (int i = 0; i < 4; ++i) {
            int r = (rbase + i * 16 + m) * G1S + q * 8;
            ah[i] = *(bf16x8*)&sAh[r];
            al[i] = *(bf16x8*)&sAl[r];
        }
#pragma unroll
        for (int j = 0; j < 4; ++j) {
            int r = (cbase + j * 16 + m) * G1S + q * 8;
            bh[j] = *(bf16x8*)&sBh[r];
            bl[j] = *(bf16x8*)&sBl[r];
        }
#pragma unroll
        for (int i = 0; i < 4; ++i)
#pragma unroll
            for (int j = 0; j < 4; ++j) {
                acc[i][j] = __builtin_amdgcn_mfma_f32_16x16x32_bf16(ah[i], bl[j], acc[i][j], 0, 0, 0);
                acc[i][j] = __builtin_amdgcn_mfma_f32_16x16x32_bf16(al[i], bh[j], acc[i][j], 0, 0, 0);
                acc[i][j] = __builtin_amdgcn_mfma_f32_16x16x32_bf16(ah[i], bh[j], acc[i][j], 0, 0, 0);
            }
        __syncthreads();
    }
    // epilogue: C/D layout col=lane&15, row=quad*4+reg
#pragma unroll
    for (int i = 0; i < 4; ++i)
#pragma unroll
        for (int j = 0; j < 4; ++j) {
            int col = col0 + cbase + j * 16 + m;
#pragma unroll
            for (int r = 0; r < 4; ++r) {
                int row = row0 + rbase + i * 16 + q * 4 + r;
                if (row < M) h1b[(size_t)row * 256 + col] = bf16_rne(acc[i][j][r]);
            }
        }
}

// ---------------- alpha1 from bf16 h1 ----------------
__global__ __launch_bounds__(256) void k_alpha1(const unsigned short* __restrict__ h1b,
                                                const float* __restrict__ a1s,
                                                const float* __restrict__ a1d,
                                                float* __restrict__ as_,
                                                float* __restrict__ ad_, int N) {
    int wid = (blockIdx.x * blockDim.x + threadIdx.x) >> 6;
    int lane = threadIdx.x & 63;
    if (wid >= N) return;
    u16x4 hv = *(const u16x4*)&h1b[(size_t)wid * 256 + lane * 4];
    float4 s = *(const float4*)&a1s[lane * 4];
    float4 d = *(const float4*)&a1d[lane * 4];
    float h0 = bf16_to_f(hv.x), h1 = bf16_to_f(hv.y);
    float h2 = bf16_to_f(hv.z), h3 = bf16_to_f(hv.w);
    float ps = h0 * s.x + h1 * s.y + h2 * s.z + h3 * s.w;
    float pd = h0 * d.x + h1 * d.y + h2 * d.z + h3 * d.w;
#pragma unroll
    for (int m = 1; m < 32; m <<= 1) {
        ps += __shfl_xor(ps, m, 64);
        pd += __shfl_xor(pd, m, 64);
    }
    if ((lane & 31) == 0) {
        int hh = lane >> 5;
        as_[wid * 2 + hh] = ps;
        ad_[wid * 2 + hh] = pd;
    }
}

// ---------------- layer-1 aggregate: single-pass, bf16 gather ----------------
__global__ __launch_bounds__(256) void k_agg1(const unsigned short* __restrict__ h1b,
                                              const float* __restrict__ as,
                                              const float* __restrict__ ad,
                                              const int* __restrict__ off,
                                              const int* __restrict__ srcl,
                                              const float* __restrict__ b1,
                                              float* __restrict__ out, int N) {
    int wid = (blockIdx.x * blockDim.x + threadIdx.x) >> 6;
    int lane = threadIdx.x & 63;
    if (wid >= N) return;
    int p0 = off[wid], p1 = off[wid + 1];
    float ad0 = ad[wid * 2], ad1 = ad[wid * 2 + 1];
    int head = lane >> 5;
    float4 acc = make_float4(0.f, 0.f, 0.f, 0.f);
    float sumw = 0.f;
    for (int base = p0; base < p1; base += 64) {
        int p = base + lane;
        int cnt = min(64, p1 - base);
        int s = 0; float w0 = 0.f, w1 = 0.f;
        if (p < p1) {
            s = srcl[p];
            float l0 = as[s * 2] + ad0;     l0 = l0 >= 0.f ? l0 : NSLOPE * l0;
            float l1 = as[s * 2 + 1] + ad1; l1 = l1 >= 0.f ? l1 : NSLOPE * l1;
            w0 = __expf(l0); w1 = __expf(l1);  // logits bounded; no max shift needed
        }
        for (int j = 0; j < cnt; ++j) {
            int sj = __shfl(s, j, 64);
            float wj0 = __shfl(w0, j, 64);
            float wj1 = __shfl(w1, j, 64);
            float wj = head ? wj1 : wj0;
            sumw += wj;
            u16x4 hv = *(const u16x4*)&h1b[(size_t)sj * 256 + lane * 4];
            acc.x += wj * bf16_to_f(hv.x);
            acc.y += wj * bf16_to_f(hv.y);
            acc.z += wj * bf16_to_f(hv.z);
            acc.w += wj * bf16_to_f(hv.w);
        }
    }
    float inv = 1.0f / sumw;
    float4 bv = *(const float4*)&b1[lane * 4];
    float4 o;
    o.x = acc.x * inv + bv.x; o.y = acc.y * inv + bv.y;
    o.z = acc.z * inv + bv.z; o.w = acc.w * inv + bv.w;
    o.x = o.x > 0.f ? o.x : expm1f(o.x);
    o.y = o.y > 0.f ? o.y : expm1f(o.y);
    o.z = o.z > 0.f ? o.z : expm1f(o.z);
    o.w = o.w > 0.f ? o.w : expm1f(o.w);
    *(float4*)&out[(size_t)wid * 256 + lane * 4] = o;
}

// ---------------- GEMM2: fp32 vector 64x64, alpha2 fused, bf16 h2 out ------
__global__ __launch_bounds__(128) void k_gemm2(const float* __restrict__ x,
                                               const float* __restrict__ W,
                                               const float* __restrict__ a2s,
                                               const float* __restrict__ a2d,
                                               unsigned short* __restrict__ h2b,
                                               float* __restrict__ as_,
                                               float* __restrict__ ad_, int M) {
    __shared__ float xs[32][68];
    __shared__ float ws[32][68];
    int t = threadIdx.x;
    int tx = t & 7, ty = t >> 3;
    int row0 = blockIdx.x * 64;
    float acc[4][8];
#pragma unroll
    for (int i = 0; i < 4; ++i)
#pragma unroll
        for (int j = 0; j < 8; ++j) acc[i][j] = 0.f;

    for (int kc = 0; kc < 256; kc += 32) {
#pragma unroll
        for (int j = 0; j < 4; ++j) {
            int slot = t + j * 128;
            int r = slot >> 3, kg = slot & 7;
            int row = row0 + r;
            float4 v = make_float4(0.f, 0.f, 0.f, 0.f);
            if (row < M) v = *(const float4*)&x[(size_t)row * 256 + kc + kg * 4];
            xs[kg * 4 + 0][r] = v.x; xs[kg * 4 + 1][r] = v.y;
            xs[kg * 4 + 2][r] = v.z; xs[kg * 4 + 3][r] = v.w;
        }
#pragma unroll
        for (int j = 0; j < 4; ++j) {
            int slot = t + j * 128;
            int k = slot >> 4, cg = slot & 15;
            *(float4*)&ws[k][cg * 4] =
                *(const float4*)&W[(size_t)(kc + k) * 64 + cg * 4];
        }
        __syncthreads();
#pragma unroll 8
        for (int k = 0; k < 32; ++k) {
            float4 a  = *(const float4*)&xs[k][ty * 4];
            float4 b0 = *(const float4*)&ws[k][tx * 4];
            float4 b1 = *(const float4*)&ws[k][32 + tx * 4];
            float av[4] = {a.x, a.y, a.z, a.w};
            float bv[8] = {b0.x, b0.y, b0.z, b0.w, b1.x, b1.y, b1.z, b1.w};
#pragma unroll
            for (int i = 0; i < 4; ++i)
#pragma unroll
                for (int j = 0; j < 8; ++j) acc[i][j] += av[i] * bv[j];
        }
        __syncthreads();
    }

    float4 s0 = *(const float4*)&a2s[tx * 4];
    float4 s1 = *(const float4*)&a2s[32 + tx * 4];
    float4 d0 = *(const float4*)&a2d[tx * 4];
    float4 d1 = *(const float4*)&a2d[32 + tx * 4];
#pragma unroll
    for (int i = 0; i < 4; ++i) {
        int row = row0 + ty * 4 + i;
        float ps = acc[i][0] * s0.x + acc[i][1] * s0.y + acc[i][2] * s0.z + acc[i][3] * s0.w
                 + acc[i][4] * s1.x + acc[i][5] * s1.y + acc[i][6] * s1.z + acc[i][7] * s1.w;
        float pd = acc[i][0] * d0.x + acc[i][1] * d0.y + acc[i][2] * d0.z + acc[i][3] * d0.w
                 + acc[i][4] * d1.x + acc[i][5] * d1.y + acc[i][6] * d1.z + acc[i][7] * d1.w;
#pragma unroll
        for (int m = 1; m < 8; m <<= 1) {
            ps += __shfl_xor(ps, m, 64);
            pd += __shfl_xor(pd, m, 64);
        }
        if (row < M) {
            unsigned short o0[4], o1[4];
#pragma unroll
            for (int c = 0; c < 4; ++c) {
                o0[c] = bf16_rne(acc[i][c]);
                o1[c] = bf16_rne(acc[i][4 + c]);
            }
            *(u16x4*)&h2b[(size_t)row * 64 + tx * 4]      = *(u16x4*)o0;
            *(u16x4*)&h2b[(size_t)row * 64 + 32 + tx * 4] = *(u16x4*)o1;
            if (tx == 0) { as_[row] = ps; ad_[row] = pd; }
        }
    }
}

// ---------------- layer-2 aggregate: single-pass, bf16 gather ----------------
__global__ __launch_bounds__(256) void k_agg2(const unsigned short* __restrict__ h2b,
                                              const float* __restrict__ as,
                                              const float* __restrict__ ad,
                                              const int* __restrict__ off,
                                              const int* __restrict__ srcl,
                                              const float* __restrict__ b2,
                                              float* __restrict__ out, int N) {
    int wid = (blockIdx.x * blockDim.x + threadIdx.x) >> 6;
    int lane = threadIdx.x & 63;
    if (wid >= N) return;
    int p0 = off[wid], p1 = off[wid + 1];
    float adw = ad[wid];
    float acc = 0.f, sumw = 0.f;
    for (int base = p0; base < p1; base += 64) {
        int p = base + lane;
        int cnt = min(64, p1 - base);
        int s = 0; float w = 0.f;
        if (p < p1) {
            s = srcl[p];
            float l = as[s] + adw;
            l = l >= 0.f ? l : NSLOPE * l;
            w = __expf(l);
        }
        for (int j = 0; j < cnt; ++j) {
            int sj = __shfl(s, j, 64);
            float wj = __shfl(w, j, 64);
            sumw += wj;
            acc += wj * bf16_to_f(h2b[(size_t)sj * 64 + lane]);
        }
    }
    out[(size_t)wid * 64 + lane] = acc / sumw + b2[lane];
}

// ---------------- launch ----------------
extern "C" void kernel_launch(void* const* d_in, const int* in_sizes, int n_in,
                              void* d_out, int out_size, void* d_ws, size_t ws_size,
                              hipStream_t stream) {
    if (n_in < 10) return;
    const float* x   = (const float*)d_in[0];
    const int*   ei  = (const int*)d_in[1];
    const float* W1  = (const float*)d_in[2];
    const float* a1s = (const float*)d_in[3];
    const float* a1d = (const float*)d_in[4];
    const float* b1  = (const float*)d_in[5];
    const float* W2  = (const float*)d_in[6];
    const float* a2s = (const float*)d_in[7];
    const float* a2d = (const float*)d_in[8];
    const float* b2  = (const float*)d_in[9];
    float* out = (float*)d_out;

    const int N = in_sizes[0] / 256;
    const int E = in_sizes[1] / 2;
    const int* esrc = ei;
    const int* edst = ei + E;

    char* ws = (char*)d_ws;
    size_t o = 0;
    auto alloc = [&](size_t bytes) -> void* {
        void* p = ws + o;
        o = (o + bytes + 255) & ~(size_t)255;
        return p;
    };
    // region A: Xhi+Xlo (dead after gemm1) aliased with helu (written by agg1)
    size_t szX = (size_t)N * 256 * 2;
    char* regionA = (char*)alloc(2 * szX);  // 51.2 MB
    unsigned short* Xhi = (unsigned short*)regionA;
    unsigned short* Xlo = (unsigned short*)(regionA + szX);
    float* helu = (float*)regionA;  // [N][256] f32 == 2*szX bytes

    unsigned short* h1b = (unsigned short*)alloc((size_t)N * 256 * 2);
    unsigned short* Whi = (unsigned short*)alloc(256 * 256 * 2);
    unsigned short* Wlo = (unsigned short*)alloc(256 * 256 * 2);
    unsigned short* h2b = (unsigned short*)alloc((size_t)N * 64 * 2);
    float* al1s = (float*)alloc((size_t)N * 2 * 4);
    float* al1d = (float*)alloc((size_t)N * 2 * 4);
    float* al2s = (float*)alloc((size_t)N * 4);
    float* al2d = (float*)alloc((size_t)N * 4);
    int* deg  = (int*)alloc((size_t)N * 4);
    int* off  = (int*)alloc((size_t)(N + 1) * 4);
    int* cur  = (int*)alloc((size_t)N * 4);
    int* part = (int*)alloc(256 * 4);
    int* srcl = (int*)alloc((size_t)(E + N) * 4);
    if (o > ws_size) return;

    const int CH = (N + 255) / 256;

    // CSR build
    k_init_deg<<<(N + 255) / 256, 256, 0, stream>>>(deg, N);
    k_hist<<<(E + 255) / 256, 256, 0, stream>>>(edst, deg, E);
    k_scan_a<<<256, 256, 0, stream>>>(deg, part, N, CH);
    k_scan_b<<<1, 256, 0, stream>>>(part, &off[N]);
    k_scan_c<<<256, 256, 0, stream>>>(deg, part, off, cur, N, CH);
    k_fill<<<(E + N + 255) / 256, 256, 0, stream>>>(esrc, edst, cur, srcl, E, N);

    // prep splits
    k_prepw<<<64, 256, 0, stream>>>(W1, Whi, Wlo);
    int total4 = N * 64;  // N*256/4
    k_prepx<<<(total4 + 255) / 256, 256, 0, stream>>>(x, Xhi, Xlo, total4);

    // layer 1
    dim3 g1((N + 127) / 128, 2);
    k_gemm1<<<g1, 256, 0, stream>>>(Xhi, Xlo, Whi, Wlo, h1b, N);
    k_alpha1<<<(N + 3) / 4, 256, 0, stream>>>(h1b, a1s, a1d, al1s, al1d, N);
    k_agg1<<<(N + 3) / 4, 256, 0, stream>>>(h1b, al1s, al1d, off, srcl, b1, helu, N);

    // layer 2
    k_gemm2<<<(N + 63) / 64, 128, 0, stream>>>(helu, W2, a2s, a2d, h2b, al2s, al2d, N);
    k_agg2<<<(N + 3) / 4, 256, 0, stream>>>(h2b, al2s, al2d, off, srcl, b2, out, N);
}

// Round 4
// 310.497 us; speedup vs baseline: 1.9572x; 1.1990x over previous
//
#include <hip/hip_runtime.h>
#include <hip/hip_bf16.h>
#include <math.h>

// GAT encoder, round 4.
//  - gemm1 (x@W1): split-bf16 MFMA (3-term), 128x128 tiles, alpha1 FUSED in epilogue.
//  - agg1: half-wave-per-edge (u16x8 gathers), single-pass softmax, bf16 helu out.
//  - gemm2 (helu@W2): bf16-A x split-bf16-B MFMA, alpha2 fused.
//  - agg2: quarter-wave-per-edge (u16x4 gathers).

#define NSLOPE 0.2f

using bf16x8 = __attribute__((ext_vector_type(8))) short;
using f32x4  = __attribute__((ext_vector_type(4))) float;
using u16x8  = __attribute__((ext_vector_type(8))) unsigned short;
using u16x4  = __attribute__((ext_vector_type(4))) unsigned short;

__device__ __forceinline__ unsigned short bf16_rne(float f) {
    unsigned u = __float_as_uint(f);
    return (unsigned short)((u + 0x7FFFu + ((u >> 16) & 1u)) >> 16);
}
__device__ __forceinline__ float bf16_to_f(unsigned short h) {
    return __uint_as_float(((unsigned)h) << 16);
}

// ---------------- CSR build ----------------
__global__ void k_init_deg(int* deg, int n) {
    int i = blockIdx.x * blockDim.x + threadIdx.x;
    if (i < n) deg[i] = 1;  // self-loop
}

__global__ void k_hist(const int* __restrict__ dst, int* deg, int E) {
    int i = blockIdx.x * blockDim.x + threadIdx.x;
    if (i < E) atomicAdd(&deg[dst[i]], 1);
}

__global__ __launch_bounds__(256) void k_scan_a(const int* __restrict__ deg,
                                                int* __restrict__ part, int n, int CH) {
    __shared__ int sd[256];
    int b = blockIdx.x, t = threadIdx.x;
    int s = b * CH, e = min(n, s + CH);
    int loc = 0;
    for (int i = s + t; i < e; i += 256) loc += deg[i];
    sd[t] = loc;
    __syncthreads();
    for (int o = 128; o > 0; o >>= 1) {
        if (t < o) sd[t] += sd[t + o];
        __syncthreads();
    }
    if (t == 0) part[b] = sd[0];
}

__global__ __launch_bounds__(256) void k_scan_b(int* part, int* off_n) {
    __shared__ int sd[256];
    int t = threadIdx.x;
    int v = part[t];
    sd[t] = v;
    __syncthreads();
    for (int o = 1; o < 256; o <<= 1) {
        int u = (t >= o) ? sd[t - o] : 0;
        __syncthreads();
        sd[t] += u;
        __syncthreads();
    }
    part[t] = sd[t] - v;
    if (t == 255) *off_n = sd[255];
}

__global__ __launch_bounds__(256) void k_scan_c(const int* __restrict__ deg,
                                                const int* __restrict__ part,
                                                int* __restrict__ off,
                                                int* __restrict__ cur, int n, int CH) {
    __shared__ int sd[256];
    int b = blockIdx.x, t = threadIdx.x;
    int s = b * CH, e = min(n, s + CH);
    int base = part[b];
    for (int c = s; c < e; c += 256) {
        int i = c + t;
        int v = (i < e) ? deg[i] : 0;
        sd[t] = v;
        __syncthreads();
        for (int o = 1; o < 256; o <<= 1) {
            int u = (t >= o) ? sd[t - o] : 0;
            __syncthreads();
            sd[t] += u;
            __syncthreads();
        }
        if (i < e) {
            int ex = base + sd[t] - v;
            off[i] = ex; cur[i] = ex;
        }
        base += sd[255];
        __syncthreads();
    }
}

__global__ void k_fill(const int* __restrict__ src, const int* __restrict__ dst,
                       int* cur, int* __restrict__ srcl, int E, int N) {
    int i = blockIdx.x * blockDim.x + threadIdx.x;
    if (i >= E + N) return;
    int s, d;
    if (i < E) { s = src[i]; d = dst[i]; } else { s = d = i - E; }
    int p = atomicAdd(&cur[d], 1);
    srcl[p] = s;
}

// ---------------- prep: split W1 (transpose to [n][k]) ----------------
__global__ __launch_bounds__(256) void k_prepw(const float* __restrict__ W,
                                               unsigned short* __restrict__ Whi,
                                               unsigned short* __restrict__ Wlo) {
    int id = blockIdx.x * 256 + threadIdx.x;  // 16384 threads
    int n = id >> 6, kg = id & 63;
    unsigned short hi[4], lo[4];
#pragma unroll
    for (int c = 0; c < 4; ++c) {
        float w = W[(kg * 4 + c) * 256 + n];
        unsigned short h = bf16_rne(w);
        hi[c] = h;
        lo[c] = bf16_rne(w - bf16_to_f(h));
    }
    *(u16x4*)&Whi[n * 256 + kg * 4] = *(u16x4*)hi;
    *(u16x4*)&Wlo[n * 256 + kg * 4] = *(u16x4*)lo;
}

// ---------------- prep: split W2 (transpose to [n][k], n=64,k=256) ----------
__global__ __launch_bounds__(256) void k_prepw2(const float* __restrict__ W,
                                                unsigned short* __restrict__ Whi,
                                                unsigned short* __restrict__ Wlo) {
    int id = blockIdx.x * 256 + threadIdx.x;  // 16384
    int n = id >> 8, k = id & 255;
    float w = W[k * 64 + n];
    unsigned short h = bf16_rne(w);
    Whi[n * 256 + k] = h;
    Wlo[n * 256 + k] = bf16_rne(w - bf16_to_f(h));
}

// ---------------- prep: split x ----------------
__global__ __launch_bounds__(256) void k_prepx(const float* __restrict__ x,
                                               unsigned short* __restrict__ Xhi,
                                               unsigned short* __restrict__ Xlo,
                                               int total4) {
    int id = blockIdx.x * 256 + threadIdx.x;
    if (id >= total4) return;
    float4 v = *(const float4*)&x[(size_t)id * 4];
    float vv[4] = {v.x, v.y, v.z, v.w};
    unsigned short hi[4], lo[4];
#pragma unroll
    for (int c = 0; c < 4; ++c) {
        unsigned short h = bf16_rne(vv[c]);
        hi[c] = h;
        lo[c] = bf16_rne(vv[c] - bf16_to_f(h));
    }
    *(u16x4*)&Xhi[(size_t)id * 4] = *(u16x4*)hi;
    *(u16x4*)&Xlo[(size_t)id * 4] = *(u16x4*)lo;
}

// ---------------- GEMM1: split-bf16 MFMA, 128x128 tile, alpha1 fused --------
#define G1S 40  // LDS row stride in ushort (32 k + 8 pad)
__global__ __launch_bounds__(256) void k_gemm1(const unsigned short* __restrict__ Xhi,
                                               const unsigned short* __restrict__ Xlo,
                                               const unsigned short* __restrict__ Whi,
                                               const unsigned short* __restrict__ Wlo,
                                               const float* __restrict__ a1s,
                                               const float* __restrict__ a1d,
                                               unsigned short* __restrict__ h1b,
                                               float* __restrict__ as_,
                                               float* __restrict__ ad_, int M) {
    __shared__ unsigned short sAh[128 * G1S], sAl[128 * G1S];
    __shared__ unsigned short sBh[128 * G1S], sBl[128 * G1S];
    __shared__ float salS[128][2], salD[128][2];
    int t = threadIdx.x;
    int lane = t & 63, wave = t >> 6;
    int q = lane >> 4, m = lane & 15;
    int row0 = blockIdx.x * 128;
    int head = blockIdx.y;
    int col0 = head * 128;
    int rbase = (wave & 1) * 64, cbase = (wave >> 1) * 64;
    f32x4 acc[4][4];
#pragma unroll
    for (int i = 0; i < 4; ++i)
#pragma unroll
        for (int j = 0; j < 4; ++j) acc[i][j] = (f32x4){0.f, 0.f, 0.f, 0.f};

    for (int kc = 0; kc < 256; kc += 32) {
#pragma unroll
        for (int i = 0; i < 2; ++i) {
            int slot = t + i * 256;
            int r = slot >> 2, kg = slot & 3;
            int row = row0 + r;
            u16x8 vh = {0, 0, 0, 0, 0, 0, 0, 0};
            u16x8 vl = {0, 0, 0, 0, 0, 0, 0, 0};
            if (row < M) {
                vh = *(const u16x8*)&Xhi[(size_t)row * 256 + kc + kg * 8];
                vl = *(const u16x8*)&Xlo[(size_t)row * 256 + kc + kg * 8];
            }
            *(u16x8*)&sAh[r * G1S + kg * 8] = vh;
            *(u16x8*)&sAl[r * G1S + kg * 8] = vl;
        }
#pragma unroll
        for (int i = 0; i < 2; ++i) {
            int slot = t + i * 256;
            int n = slot >> 2, kg = slot & 3;
            *(u16x8*)&sBh[n * G1S + kg * 8] =
                *(const u16x8*)&Whi[(size_t)(col0 + n) * 256 + kc + kg * 8];
            *(u16x8*)&sBl[n * G1S + kg * 8] =
                *(const u16x8*)&Wlo[(size_t)(col0 + n) * 256 + kc + kg * 8];
        }
        __syncthreads();
        bf16x8 ah[4], al[4], bh[4], bl[4];
#pragma unroll
        for (int i = 0; i < 4; ++i) {
            int r = (rbase + i * 16 + m) * G1S + q * 8;
            ah[i] = *(bf16x8*)&sAh[r];
            al[i] = *(bf16x8*)&sAl[r];
        }
#pragma unroll
        for (int j = 0; j < 4; ++j) {
            int r = (cbase + j * 16 + m) * G1S + q * 8;
            bh[j] = *(bf16x8*)&sBh[r];
            bl[j] = *(bf16x8*)&sBl[r];
        }
#pragma unroll
        for (int i = 0; i < 4; ++i)
#pragma unroll
            for (int j = 0; j < 4; ++j) {
                acc[i][j] = __builtin_amdgcn_mfma_f32_16x16x32_bf16(ah[i], bl[j], acc[i][j], 0, 0, 0);
                acc[i][j] = __builtin_amdgcn_mfma_f32_16x16x32_bf16(al[i], bh[j], acc[i][j], 0, 0, 0);
                acc[i][j] = __builtin_amdgcn_mfma_f32_16x16x32_bf16(ah[i], bh[j], acc[i][j], 0, 0, 0);
            }
        __syncthreads();
    }
    // alpha vectors for this wave's 64 cols
    float sv[4], dv[4];
#pragma unroll
    for (int j = 0; j < 4; ++j) {
        sv[j] = a1s[head * 128 + cbase + j * 16 + m];
        dv[j] = a1d[head * 128 + cbase + j * 16 + m];
    }
    // epilogue: C/D layout col=lane&15, row=quad*4+reg
#pragma unroll
    for (int i = 0; i < 4; ++i) {
#pragma unroll
        for (int r = 0; r < 4; ++r) {
            int rl = rbase + i * 16 + q * 4 + r;
            int row = row0 + rl;
            float ps = acc[i][0][r] * sv[0] + acc[i][1][r] * sv[1]
                     + acc[i][2][r] * sv[2] + acc[i][3][r] * sv[3];
            float pd = acc[i][0][r] * dv[0] + acc[i][1][r] * dv[1]
                     + acc[i][2][r] * dv[2] + acc[i][3][r] * dv[3];
#pragma unroll
            for (int mask = 1; mask < 16; mask <<= 1) {
                ps += __shfl_xor(ps, mask, 64);
                pd += __shfl_xor(pd, mask, 64);
            }
            if (m == 0) {
                salS[rl][cbase >> 6] = ps;
                salD[rl][cbase >> 6] = pd;
            }
            if (row < M) {
#pragma unroll
                for (int j = 0; j < 4; ++j)
                    h1b[(size_t)row * 256 + col0 + cbase + j * 16 + m] = bf16_rne(acc[i][j][r]);
            }
        }
    }
    __syncthreads();
    if (t < 128) {
        int row = row0 + t;
        if (row < M) {
            as_[row * 2 + head] = salS[t][0] + salS[t][1];
            ad_[row * 2 + head] = salD[t][0] + salD[t][1];
        }
    }
}

// ---------------- layer-1 aggregate: half-wave per edge, bf16 out ----------
__global__ __launch_bounds__(256) void k_agg1(const unsigned short* __restrict__ h1b,
                                              const float* __restrict__ as,
                                              const float* __restrict__ ad,
                                              const int* __restrict__ off,
                                              const int* __restrict__ srcl,
                                              const float* __restrict__ b1,
                                              unsigned short* __restrict__ helu_b, int N) {
    int wid = (blockIdx.x * blockDim.x + threadIdx.x) >> 6;
    int lane = threadIdx.x & 63;
    if (wid >= N) return;
    int p0 = off[wid], p1 = off[wid + 1];
    float ad0 = ad[wid * 2], ad1 = ad[wid * 2 + 1];
    int half = lane >> 5, hl = lane & 31;
    int headL = hl >> 4;  // channels hl*8..+8 all in one head
    float acc[8];
#pragma unroll
    for (int c = 0; c < 8; ++c) acc[c] = 0.f;
    float sumw = 0.f;
    for (int base = p0; base < p1; base += 64) {
        int p = base + lane;
        int cnt = min(64, p1 - base);
        int s = 0; float w0 = 0.f, w1 = 0.f;
        if (p < p1) {
            s = srcl[p];
            float2 av = *(const float2*)&as[s * 2];
            float l0 = av.x + ad0; l0 = l0 >= 0.f ? l0 : NSLOPE * l0;
            float l1 = av.y + ad1; l1 = l1 >= 0.f ? l1 : NSLOPE * l1;
            w0 = __expf(l0); w1 = __expf(l1);
        }
        int pairs = (cnt + 1) >> 1;
        for (int jj = 0; jj < pairs; ++jj) {
            int e = 2 * jj + half;
            int sj   = __shfl(s, e, 64);
            float w0j = __shfl(w0, e, 64);
            float w1j = __shfl(w1, e, 64);
            float wj = headL ? w1j : w0j;
            sumw += wj;
            u16x8 hv = *(const u16x8*)&h1b[(size_t)sj * 256 + hl * 8];
#pragma unroll
            for (int c = 0; c < 8; ++c) acc[c] += wj * bf16_to_f(hv[c]);
        }
    }
#pragma unroll
    for (int c = 0; c < 8; ++c) acc[c] += __shfl_xor(acc[c], 32, 64);
    sumw += __shfl_xor(sumw, 32, 64);
    float inv = 1.0f / sumw;
    int ch = hl * 8 + half * 4;
    float4 bv = *(const float4*)&b1[ch];
    float bb[4] = {bv.x, bv.y, bv.z, bv.w};
    unsigned short o[4];
#pragma unroll
    for (int c = 0; c < 4; ++c) {
        float v = acc[half * 4 + c] * inv + bb[c];
        v = v > 0.f ? v : expm1f(v);
        o[c] = bf16_rne(v);
    }
    *(u16x4*)&helu_b[(size_t)wid * 256 + ch] = *(u16x4*)o;
}

// ---------------- GEMM2: bf16-A x split-bf16-B MFMA, alpha2 fused ----------
__global__ __launch_bounds__(256) void k_gemm2(const unsigned short* __restrict__ hb,
                                               const unsigned short* __restrict__ Whi,
                                               const unsigned short* __restrict__ Wlo,
                                               const float* __restrict__ a2s,
                                               const float* __restrict__ a2d,
                                               unsigned short* __restrict__ h2b,
                                               float* __restrict__ as_,
                                               float* __restrict__ ad_, int M) {
    __shared__ unsigned short sA[128 * G1S];
    __shared__ unsigned short sBh[64 * G1S], sBl[64 * G1S];
    int t = threadIdx.x;
    int lane = t & 63, wave = t >> 6;
    int q = lane >> 4, m = lane & 15;
    int row0 = blockIdx.x * 128;
    int rbase = wave * 32;
    f32x4 acc[2][4];
#pragma unroll
    for (int i = 0; i < 2; ++i)
#pragma unroll
        for (int j = 0; j < 4; ++j) acc[i][j] = (f32x4){0.f, 0.f, 0.f, 0.f};

    for (int kc = 0; kc < 256; kc += 32) {
#pragma unroll
        for (int i = 0; i < 2; ++i) {
            int slot = t + i * 256;
            int r = slot >> 2, kg = slot & 3;
            int row = row0 + r;
            u16x8 v = {0, 0, 0, 0, 0, 0, 0, 0};
            if (row < M) v = *(const u16x8*)&hb[(size_t)row * 256 + kc + kg * 8];
            *(u16x8*)&sA[r * G1S + kg * 8] = v;
        }
        {
            int n = t >> 2, kg = t & 3;
            *(u16x8*)&sBh[n * G1S + kg * 8] =
                *(const u16x8*)&Whi[(size_t)n * 256 + kc + kg * 8];
            *(u16x8*)&sBl[n * G1S + kg * 8] =
                *(const u16x8*)&Wlo[(size_t)n * 256 + kc + kg * 8];
        }
        __syncthreads();
        bf16x8 a[2], bh[4], bl[4];
#pragma unroll
        for (int i = 0; i < 2; ++i)
            a[i] = *(bf16x8*)&sA[(rbase + i * 16 + m) * G1S + q * 8];
#pragma unroll
        for (int j = 0; j < 4; ++j) {
            bh[j] = *(bf16x8*)&sBh[(j * 16 + m) * G1S + q * 8];
            bl[j] = *(bf16x8*)&sBl[(j * 16 + m) * G1S + q * 8];
        }
#pragma unroll
        for (int i = 0; i < 2; ++i)
#pragma unroll
            for (int j = 0; j < 4; ++j) {
                acc[i][j] = __builtin_amdgcn_mfma_f32_16x16x32_bf16(a[i], bl[j], acc[i][j], 0, 0, 0);
                acc[i][j] = __builtin_amdgcn_mfma_f32_16x16x32_bf16(a[i], bh[j], acc[i][j], 0, 0, 0);
            }
        __syncthreads();
    }
    float sv[4], dv[4];
#pragma unroll
    for (int j = 0; j < 4; ++j) {
        sv[j] = a2s[j * 16 + m];
        dv[j] = a2d[j * 16 + m];
    }
#pragma unroll
    for (int i = 0; i < 2; ++i) {
#pragma unroll
        for (int r = 0; r < 4; ++r) {
            int row = row0 + rbase + i * 16 + q * 4 + r;
            float ps = acc[i][0][r] * sv[0] + acc[i][1][r] * sv[1]
                     + acc[i][2][r] * sv[2] + acc[i][3][r] * sv[3];
            float pd = acc[i][0][r] * dv[0] + acc[i][1][r] * dv[1]
                     + acc[i][2][r] * dv[2] + acc[i][3][r] * dv[3];
#pragma unroll
            for (int mask = 1; mask < 16; mask <<= 1) {
                ps += __shfl_xor(ps, mask, 64);
                pd += __shfl_xor(pd, mask, 64);
            }
            if (row < M) {
#pragma unroll
                for (int j = 0; j < 4; ++j)
                    h2b[(size_t)row * 64 + j * 16 + m] = bf16_rne(acc[i][j][r]);
                if (m == 0) { as_[row] = ps; ad_[row] = pd; }
            }
        }
    }
}

// ---------------- layer-2 aggregate: quarter-wave per edge ----------------
__global__ __launch_bounds__(256) void k_agg2(const unsigned short* __restrict__ h2b,
                                              const float* __restrict__ as,
                                              const float* __restrict__ ad,
                                              const int* __restrict__ off,
                                              const int* __restrict__ srcl,
                                              const float* __restrict__ b2,
                                              float* __restrict__ out, int N) {
    int wid = (blockIdx.x * blockDim.x + threadIdx.x) >> 6;
    int lane = threadIdx.x & 63;
    if (wid >= N) return;
    int p0 = off[wid], p1 = off[wid + 1];
    float adw = ad[wid];
    int g = lane >> 4, gl = lane & 15;
    float acc[4];
#pragma unroll
    for (int c = 0; c < 4; ++c) acc[c] = 0.f;
    float sumw = 0.f;
    for (int base = p0; base < p1; base += 64) {
        int p = base + lane;
        int cnt = min(64, p1 - base);
        int s = 0; float w = 0.f;
        if (p < p1) {
            s = srcl[p];
            float l = as[s] + adw;
            l = l >= 0.f ? l : NSLOPE * l;
            w = __expf(l);
        }
        int quads = (cnt + 3) >> 2;
        for (int jj = 0; jj < quads; ++jj) {
            int e = 4 * jj + g;
            int sj = __shfl(s, e, 64);
            float wj = __shfl(w, e, 64);
            sumw += wj;
            u16x4 hv = *(const u16x4*)&h2b[(size_t)sj * 64 + gl * 4];
            acc[0] += wj * bf16_to_f(hv.x);
            acc[1] += wj * bf16_to_f(hv.y);
            acc[2] += wj * bf16_to_f(hv.z);
            acc[3] += wj * bf16_to_f(hv.w);
        }
    }
#pragma unroll
    for (int c = 0; c < 4; ++c) {
        acc[c] += __shfl_xor(acc[c], 16, 64);
        acc[c] += __shfl_xor(acc[c], 32, 64);
    }
    sumw += __shfl_xor(sumw, 16, 64);
    sumw += __shfl_xor(sumw, 32, 64);
    if (g == 0) {
        float inv = 1.0f / sumw;
        float4 bv = *(const float4*)&b2[gl * 4];
        float4 o;
        o.x = acc[0] * inv + bv.x;
        o.y = acc[1] * inv + bv.y;
        o.z = acc[2] * inv + bv.z;
        o.w = acc[3] * inv + bv.w;
        *(float4*)&out[(size_t)wid * 64 + gl * 4] = o;
    }
}

// ---------------- launch ----------------
extern "C" void kernel_launch(void* const* d_in, const int* in_sizes, int n_in,
                              void* d_out, int out_size, void* d_ws, size_t ws_size,
                              hipStream_t stream) {
    if (n_in < 10) return;
    const float* x   = (const float*)d_in[0];
    const int*   ei  = (const int*)d_in[1];
    const float* W1  = (const float*)d_in[2];
    const float* a1s = (const float*)d_in[3];
    const float* a1d = (const float*)d_in[4];
    const float* b1  = (const float*)d_in[5];
    const float* W2  = (const float*)d_in[6];
    const float* a2s = (const float*)d_in[7];
    const float* a2d = (const float*)d_in[8];
    const float* b2  = (const float*)d_in[9];
    float* out = (float*)d_out;

    const int N = in_sizes[0] / 256;
    const int E = in_sizes[1] / 2;
    const int* esrc = ei;
    const int* edst = ei + E;

    char* ws = (char*)d_ws;
    size_t o = 0;
    auto alloc = [&](size_t bytes) -> void* {
        void* p = ws + o;
        o = (o + bytes + 255) & ~(size_t)255;
        return p;
    };
    // region A: Xhi+Xlo (dead after gemm1); helu_b (bf16, 25.6MB) aliases Xhi
    size_t szX = (size_t)N * 256 * 2;
    char* regionA = (char*)alloc(2 * szX);
    unsigned short* Xhi = (unsigned short*)regionA;
    unsigned short* Xlo = (unsigned short*)(regionA + szX);
    unsigned short* helu_b = (unsigned short*)regionA;  // [N][256] bf16 == szX

    unsigned short* h1b  = (unsigned short*)alloc((size_t)N * 256 * 2);
    unsigned short* Whi  = (unsigned short*)alloc(256 * 256 * 2);
    unsigned short* Wlo  = (unsigned short*)alloc(256 * 256 * 2);
    unsigned short* W2hi = (unsigned short*)alloc(64 * 256 * 2);
    unsigned short* W2lo = (unsigned short*)alloc(64 * 256 * 2);
    unsigned short* h2b  = (unsigned short*)alloc((size_t)N * 64 * 2);
    float* al1s = (float*)alloc((size_t)N * 2 * 4);
    float* al1d = (float*)alloc((size_t)N * 2 * 4);
    float* al2s = (float*)alloc((size_t)N * 4);
    float* al2d = (float*)alloc((size_t)N * 4);
    int* deg  = (int*)alloc((size_t)N * 4);
    int* off  = (int*)alloc((size_t)(N + 1) * 4);
    int* cur  = (int*)alloc((size_t)N * 4);
    int* part = (int*)alloc(256 * 4);
    int* srcl = (int*)alloc((size_t)(E + N) * 4);
    if (o > ws_size) return;

    const int CH = (N + 255) / 256;

    // CSR build
    k_init_deg<<<(N + 255) / 256, 256, 0, stream>>>(deg, N);
    k_hist<<<(E + 255) / 256, 256, 0, stream>>>(edst, deg, E);
    k_scan_a<<<256, 256, 0, stream>>>(deg, part, N, CH);
    k_scan_b<<<1, 256, 0, stream>>>(part, &off[N]);
    k_scan_c<<<256, 256, 0, stream>>>(deg, part, off, cur, N, CH);
    k_fill<<<(E + N + 255) / 256, 256, 0, stream>>>(esrc, edst, cur, srcl, E, N);

    // prep splits
    k_prepw<<<64, 256, 0, stream>>>(W1, Whi, Wlo);
    k_prepw2<<<64, 256, 0, stream>>>(W2, W2hi, W2lo);
    int total4 = N * 64;
    k_prepx<<<(total4 + 255) / 256, 256, 0, stream>>>(x, Xhi, Xlo, total4);

    // layer 1
    dim3 g1((N + 127) / 128, 2);
    k_gemm1<<<g1, 256, 0, stream>>>(Xhi, Xlo, Whi, Wlo, a1s, a1d, h1b, al1s, al1d, N);
    k_agg1<<<(N + 3) / 4, 256, 0, stream>>>(h1b, al1s, al1d, off, srcl, b1, helu_b, N);

    // layer 2
    k_gemm2<<<(N + 127) / 128, 256, 0, stream>>>(helu_b, W2hi, W2lo, a2s, a2d, h2b, al2s, al2d, N);
    k_agg2<<<(N + 3) / 4, 256, 0, stream>>>(h2b, al2s, al2d, off, srcl, b2, out, N);
}